// Round 9
// baseline (97.800 us; speedup 1.0000x reference)
//
#include <hip/hip_runtime.h>
#include <hip/hip_bf16.h>

#define NPTS 96
#define HID  64
#define RANK 32
#define NTX  (NPTS * NPTS)   // 9216 rows of A (tx) and of B (yz)
#define LDC  (NPTS * NPTS)   // 9216 = C row length

// ws byte layout:
//   [0)        trans float[4][NPTS][RANK]  (axis-major, f contiguous)  49152 B
//   [AHI_OFF)  bf16 [NTX][RANK]  hi(ft*fx)                            589824 B
//   [ALO_OFF)  bf16 [NTX][RANK]  lo(ft*fx)                            589824 B
//   [BHI_OFF)  bf16 [NTX][RANK]  hi(fy*fz)                            589824 B
//   [BLO_OFF)  bf16 [NTX][RANK]  lo(fy*fz)                            589824 B
#define TRANS_BYTES (4 * NPTS * RANK * 4)
#define AHI_OFF TRANS_BYTES
#define ALO_OFF (AHI_OFF + NTX * RANK * 2)
#define BHI_OFF (ALO_OFF + NTX * RANK * 2)
#define BLO_OFF (BHI_OFF + NTX * RANK * 2)

typedef short s8v __attribute__((ext_vector_type(8)));
typedef float f4v __attribute__((ext_vector_type(4)));

static __device__ inline short f2bf(float f) {
    __hip_bfloat16 h = __float2bfloat16(f);   // HW cvt, RNE
    return *reinterpret_cast<short*>(&h);
}
static __device__ inline float bf2f(short s) {
    __hip_bfloat16 h = *reinterpret_cast<__hip_bfloat16*>(&s);
    return __bfloat162float(h);
}

// -------- Kernel 1: the 4 tiny MLPs -> trans[axis][n][f] --------
__global__ __launch_bounds__(64) void spinn_mlp(
    const float* __restrict__ t, const float* __restrict__ x,
    const float* __restrict__ y, const float* __restrict__ z,
    const float* __restrict__ W1, const float* __restrict__ b1,
    const float* __restrict__ W2, const float* __restrict__ b2,
    const float* __restrict__ W3, const float* __restrict__ b3,
    float* __restrict__ ws)
{
    const int n    = blockIdx.x;   // point 0..95
    const int axis = blockIdx.y;   // 0..3
    const int j    = threadIdx.x;  // 0..63

    const float* coords[4] = { t, x, y, z };
    const float c = coords[axis][n];

    __shared__ float h1[HID];
    __shared__ float h2[HID];

    h1[j] = tanhf(fmaf(c, W1[axis * HID + j], b1[axis * HID + j]));
    __syncthreads();

    float a = b2[axis * HID + j];
    #pragma unroll
    for (int k = 0; k < HID; ++k)
        a = fmaf(h1[k], W2[(axis * HID + k) * HID + j], a);
    h2[j] = tanhf(a);
    __syncthreads();

    if (j < RANK) {
        float o = b3[axis * RANK + j];
        #pragma unroll
        for (int k = 0; k < HID; ++k)
            o = fmaf(h2[k], W3[(axis * HID + k) * RANK + j], o);
        ws[(axis * NPTS + n) * RANK + j] = o;   // trans [axis][n][f]
    }
}

// -------- Kernel 2: build split-bf16 A = ft*fx and B = fy*fz --------
// hi = bf16(p), lo = bf16(p - float(hi));  p = hi + lo to ~2^-18 rel.
__global__ __launch_bounds__(256) void spinn_prep(float* __restrict__ ws)
{
    const int gid = blockIdx.x * 256 + threadIdx.x;  // 0..18431
    const int isB = gid >= NTX;
    const int row = isB ? gid - NTX : gid;
    const int i0  = row / NPTS;
    const int i1  = row % NPTS;

    const float* u = ws + (((isB ? 2 : 0) * NPTS) + i0) * RANK;  // ft or fy
    const float* v = ws + (((isB ? 3 : 1) * NPTS) + i1) * RANK;  // fx or fz
    short* dhi = (short*)((char*)ws + (isB ? BHI_OFF : AHI_OFF)) + (size_t)row * RANK;
    short* dlo = (short*)((char*)ws + (isB ? BLO_OFF : ALO_OFF)) + (size_t)row * RANK;

    #pragma unroll
    for (int k = 0; k < RANK; ++k) {
        const float p  = u[k] * v[k];
        const short hi = f2bf(p);
        const short lo = f2bf(p - bf2f(hi));
        dhi[k] = hi;
        dlo[k] = lo;
    }
}

// -------- Kernel 3: C[9216,9216] = A x B^T via split-bf16 mfma 16x16x32 ----
// OPERANDS SWAPPED (mfma(b, a)): D'[yz][tx] mapping puts 4 CONSECUTIVE yz
// (= consecutive C columns) in one lane's 4 acc regs -> one dwordx4 store
// per lane per tile. Lane l: tx = I*16 + (l&15), yz = J*16 + (l>>4)*4 + j.
// (Fragment/row mapping empirically validated by round 8: error was pure
// bf16 rounding, not layout.)
__global__ __launch_bounds__(256) void spinn_gemm(
    const float* __restrict__ ws, float* __restrict__ out)
{
    const short* Ahi = (const short*)((const char*)ws + AHI_OFF);
    const short* Alo = (const short*)((const char*)ws + ALO_OFF);
    const short* Bhi = (const short*)((const char*)ws + BHI_OFF);
    const short* Blo = (const short*)((const char*)ws + BLO_OFF);

    const int l  = threadIdx.x & 63;
    const int w  = threadIdx.x >> 6;        // 0..3
    const int I  = blockIdx.x * 4 + w;      // row tile 0..575
    const int Jb = blockIdx.y * 4;          // col tile base
    const int r  = l & 15;                  // within-tile row index
    const int kb = (l >> 4) * 8;            // k-slice base

    const size_t arow = (size_t)(I * 16 + r) * RANK + kb;
    const s8v ahi = *(const s8v*)(Ahi + arow);
    const s8v alo = *(const s8v*)(Alo + arow);

    float* obase = out + (size_t)(I * 16 + r) * LDC + (l >> 4) * 4;

    #pragma unroll
    for (int jj = 0; jj < 4; ++jj) {
        const int J = Jb + jj;
        const size_t brow = (size_t)(J * 16 + r) * RANK + kb;
        const s8v bhi = *(const s8v*)(Bhi + brow);
        const s8v blo = *(const s8v*)(Blo + brow);

        f4v acc = __builtin_amdgcn_mfma_f32_16x16x32_bf16(
            bhi, ahi, (f4v){0.f, 0.f, 0.f, 0.f}, 0, 0, 0);
        acc = __builtin_amdgcn_mfma_f32_16x16x32_bf16(bhi, alo, acc, 0, 0, 0);
        acc = __builtin_amdgcn_mfma_f32_16x16x32_bf16(blo, ahi, acc, 0, 0, 0);

        *(f4v*)(obase + J * 16) = acc;   // 16 B contiguous per lane
    }
}

extern "C" void kernel_launch(void* const* d_in, const int* in_sizes, int n_in,
                              void* d_out, int out_size, void* d_ws, size_t ws_size,
                              hipStream_t stream)
{
    const float* t  = (const float*)d_in[0];
    const float* x  = (const float*)d_in[1];
    const float* y  = (const float*)d_in[2];
    const float* z  = (const float*)d_in[3];
    const float* W1 = (const float*)d_in[4];
    const float* b1 = (const float*)d_in[5];
    const float* W2 = (const float*)d_in[6];
    const float* b2 = (const float*)d_in[7];
    const float* W3 = (const float*)d_in[8];
    const float* b3 = (const float*)d_in[9];

    float* ws  = (float*)d_ws;
    float* out = (float*)d_out;

    spinn_mlp<<<dim3(NPTS, 4), 64, 0, stream>>>(t, x, y, z, W1, b1, W2, b2, W3, b3, ws);
    spinn_prep<<<(2 * NTX) / 256, 256, 0, stream>>>(ws);
    spinn_gemm<<<dim3(NTX / 16 / 4, NTX / 16 / 4), 256, 0, stream>>>(ws, out);
}